// Round 12
// baseline (38.730 us; speedup 1.0000x reference)
//
#include <hip/hip_runtime.h>

#define F_IN    32768
#define HID     64
#define NB_OBJ  16
#define BATCH   64
#define N_AGENTS 4
#define N_ACT   13
#define NEG_SLOPE 0.01f

#define FC      64               // f-chunk width per fused block
#define NCHUNK  (F_IN / FC)      // 512 split-K chunks

typedef float f32x4 __attribute__((ext_vector_type(4)));

// static scratch: g_part[NCHUNK][BATCH][HID] = 8 MiB (split-K partials)
__device__ float g_part[NCHUNK * BATCH * HID];

__device__ __forceinline__ float rdlane(float v, int src) {
    return __int_as_float(__builtin_amdgcn_readlane(__float_as_int(v), src));
}

// ---------------------------------------------------------------------------
// K1: fused node-mean + partial GEMM — barrier-free, LDS-free.
// grid = NCHUNK (512), block = 512 (8 waves).
// Wave wv loads+averages rows 8wv..8wv+7 (lane (b&7)*8+j holds row b,
// f-quads j and j+8), then does the 64x64 dot in-register: xbar values are
// broadcast via v_readlane (compile-time src lane) as scalar fmac operands.
// No __syncthreads, no LDS: step-B VALU hides under other waves' HBM loads.
// ---------------------------------------------------------------------------
__global__ __launch_bounds__(512, 4)
void k_fused(const float* __restrict__ u, const float* __restrict__ w) {
    const int t    = threadIdx.x;
    const int blk  = blockIdx.x;
    const int f0   = blk * FC;
    const int lane = t & 63;
    const int wv   = t >> 6;                // 0..7

    // step A: lane accumulates row brow, f-quads j (f=4j..) and j+8 (f=32+4j..)
    const int brow = t >> 3;                // global batch row
    const int j    = t & 7;
    const float* up = u + (size_t)brow * (NB_OBJ * F_IN) + f0 + j * 4;
    f32x4 a0 = (f32x4)(0.f), a1 = (f32x4)(0.f);
    #pragma unroll
    for (int o = 0; o < NB_OBJ; ++o) {
        const float* ro = up + (size_t)o * F_IN;
        a0 += *reinterpret_cast<const f32x4*>(ro);
        a1 += *reinterpret_cast<const f32x4*>(ro + 32);
    }
    const float inv = 1.0f / (float)NB_OBJ;
    a0 *= inv;
    a1 *= inv;

    // w column slice: wreg[f] = w[(f0+f)*HID + lane]  (lane = output h)
    float wreg[FC];
    {
        const float* wp = w + (size_t)f0 * HID + lane;
        #pragma unroll
        for (int f = 0; f < FC; ++f) wreg[f] = wp[f * HID];
    }

    // step B: wave wv computes batches 8wv+bb; f ascending 0..63 (bitwise
    // same FP order as the LDS version). src lane = bb*8 + jj.
    float* pout = g_part + (size_t)blk * (BATCH * HID)
                + (size_t)(wv * 8) * HID + lane;
    #pragma unroll
    for (int bb = 0; bb < 8; ++bb) {
        float acc = 0.f;
        #pragma unroll
        for (int jj = 0; jj < 8; ++jj) {      // f = 4*jj + e  (0..31)
            #pragma unroll
            for (int e = 0; e < 4; ++e)
                acc += rdlane(a0[e], bb * 8 + jj) * wreg[jj * 4 + e];
        }
        #pragma unroll
        for (int jj = 0; jj < 8; ++jj) {      // f = 32 + 4*jj + e
            #pragma unroll
            for (int e = 0; e < 4; ++e)
                acc += rdlane(a1[e], bb * 8 + jj) * wreg[32 + jj * 4 + e];
        }
        pout[bb * HID] = acc;
    }
}

// ---------------------------------------------------------------------------
// K2: single merged tail (Round-11, proven). grid = BATCH (64), block = 1024.
// ---------------------------------------------------------------------------
__global__ __launch_bounds__(1024)
void k_tail(const float* __restrict__ gcn_b,
            const float* __restrict__ w1, const float* __restrict__ b1,
            const float* __restrict__ w2, const float* __restrict__ b2,
            const float* __restrict__ actions, float* __restrict__ out) {
    const int b = blockIdx.x;
    const int t = threadIdx.x;
    __shared__ float red[16][HID];
    __shared__ float pooled[HID];
    __shared__ float zbuf[N_AGENTS][HID];
    __shared__ float qbuf[N_AGENTS][N_ACT];

    // phase 1: red[kg][h] = sum of this kg's 32 chunks
    {
        const int h  = t & 63;
        const int kg = t >> 6;   // 0..15
        const float* p = g_part + (size_t)(kg * 32) * (BATCH * HID)
                       + (size_t)b * HID + h;
        float acc = 0.f;
        #pragma unroll
        for (int i = 0; i < 32; ++i)
            acc += p[(size_t)i * (BATCH * HID)];
        red[kg][h] = acc;
    }
    __syncthreads();
    if (t < HID) {
        float acc = gcn_b[t];
        #pragma unroll
        for (int kg = 0; kg < 16; ++kg) acc += red[kg][t];
        pooled[t] = acc;
    }
    __syncthreads();

    // phase 2: z[a][k] = leaky(b1 + sum_h pooled[h] * w1[a][h][k])
    if (t < N_AGENTS * HID) {
        const int a = t >> 6, k = t & 63;
        const float* w1p = w1 + a * (HID * HID) + k;
        float acc = b1[a * HID + k];
        #pragma unroll
        for (int hh = 0; hh < HID; ++hh) acc += pooled[hh] * w1p[hh * HID];
        zbuf[a][k] = (acc >= 0.f) ? acc : NEG_SLOPE * acc;
    }
    __syncthreads();

    // phase 3: q[a][c] = b2 + sum_h z[a][h] * w2[a][h][c]
    if (t < N_AGENTS * N_ACT) {
        const int a = t / N_ACT, c = t % N_ACT;
        const float* w2p = w2 + a * (HID * N_ACT) + c;
        float acc = b2[a * N_ACT + c];
        #pragma unroll
        for (int hh = 0; hh < HID; ++hh) acc += zbuf[a][hh] * w2p[hh * N_ACT];
        qbuf[a][c] = acc;
    }
    __syncthreads();

    // phase 4: argmax over actions (first-max, matching jnp.argmax), gather
    if (t < N_AGENTS) {
        const float* ap = actions + ((size_t)t * BATCH + b) * N_ACT;
        int best = 0; float bv = ap[0];
        for (int c = 1; c < N_ACT; ++c) {
            float v = ap[c];
            if (v > bv) { bv = v; best = c; }
        }
        out[t * BATCH + b] = qbuf[t][best];
    }
}

extern "C" void kernel_launch(void* const* d_in, const int* in_sizes, int n_in,
                              void* d_out, int out_size, void* d_ws, size_t ws_size,
                              hipStream_t stream) {
    const float* u   = (const float*)d_in[0];
    // d_in[1] = binary_tensor: dead in the reference computation
    const float* act = (const float*)d_in[2];
    const float* gw  = (const float*)d_in[3];
    const float* gb  = (const float*)d_in[4];
    const float* w1  = (const float*)d_in[5];
    const float* b1  = (const float*)d_in[6];
    const float* w2  = (const float*)d_in[7];
    const float* b2  = (const float*)d_in[8];
    float* out = (float*)d_out;

    hipLaunchKernelGGL(k_fused, dim3(NCHUNK), dim3(512), 0, stream, u, gw);
    hipLaunchKernelGGL(k_tail,  dim3(BATCH),  dim3(1024), 0, stream,
                       gb, w1, b1, w2, b2, act, out);
}

// Round 14
// 36.156 us; speedup vs baseline: 1.0712x; 1.0712x over previous
//
#include <hip/hip_runtime.h>

#define F_IN    32768
#define HID     64
#define NB_OBJ  16
#define BATCH   64
#define N_AGENTS 4
#define N_ACT   13
#define NEG_SLOPE 0.01f

#define FC      64               // f-chunk width per fused block
#define NCHUNK  (F_IN / FC)      // 512 split-K chunks

typedef float f32x4 __attribute__((ext_vector_type(4)));

// static scratch: g_part[BATCH][NCHUNK][HID] = 8 MiB.
// Layout [b][chunk][h]: fused stores stay 256B-coalesced; tail block b
// reads ONE contiguous 128 KiB stream (vs 512 scattered segments).
__device__ float g_part[BATCH * NCHUNK * HID];

// ---------------------------------------------------------------------------
// K1: fused node-mean + partial GEMM (R11 body, only the store layout moved
// to [b][chunk][h]). grid = NCHUNK (512), block = 512 (8 waves).
// ---------------------------------------------------------------------------
__global__ __launch_bounds__(512, 4)
void k_fused(const float* __restrict__ u, const float* __restrict__ w) {
    __shared__ float xbar[BATCH][FC + 4];   // row pitch 68 floats
    const int t    = threadIdx.x;
    const int blk  = blockIdx.x;
    const int f0   = blk * FC;
    const int lane = t & 63;
    const int wv   = t >> 6;                // 0..7

    // w column slice in registers: wreg[f] = w[(f0+f)*HID + lane]
    float wreg[FC];
    {
        const float* wp = w + (size_t)f0 * HID + lane;
        #pragma unroll
        for (int f = 0; f < FC; ++f) wreg[f] = wp[f * HID];
    }

    // step A: xbar[b][f] = (1/16) * sum_o u[b][o][f0+f]
    {
        const int b = t >> 3;
        const int j = t & 7;
        const float* up = u + (size_t)b * (NB_OBJ * F_IN) + f0 + j * 4;
        f32x4 a0 = (f32x4)(0.f);
        f32x4 a1 = (f32x4)(0.f);
        #pragma unroll
        for (int o = 0; o < NB_OBJ; ++o) {
            const float* ro = up + (size_t)o * F_IN;
            a0 += *reinterpret_cast<const f32x4*>(ro);
            a1 += *reinterpret_cast<const f32x4*>(ro + 32);
        }
        const float inv = 1.0f / (float)NB_OBJ;
        a0 *= inv;
        a1 *= inv;
        *reinterpret_cast<f32x4*>(&xbar[b][j * 4])      = a0;
        *reinterpret_cast<f32x4*>(&xbar[b][32 + j * 4]) = a1;
    }
    __syncthreads();

    // step B: each wave -> 8 batches; lane = output h. Store [b][blk][h]:
    // per (wave,bb) the 64 lanes write one contiguous 256B segment.
    {
        #pragma unroll
        for (int bb = 0; bb < 8; ++bb) {
            const int b = wv * 8 + bb;
            float acc = 0.f;
            #pragma unroll
            for (int fq = 0; fq < FC / 4; ++fq) {
                f32x4 xb = *reinterpret_cast<const f32x4*>(&xbar[b][fq * 4]);
                acc += xb.x * wreg[fq * 4 + 0];
                acc += xb.y * wreg[fq * 4 + 1];
                acc += xb.z * wreg[fq * 4 + 2];
                acc += xb.w * wreg[fq * 4 + 3];
            }
            g_part[((size_t)b * NCHUNK + blk) * HID + lane] = acc;
        }
    }
}

// ---------------------------------------------------------------------------
// K2: single merged tail. grid = BATCH (64), block = 1024 (16 waves).
// phase 1: thread (kg = t>>6 in 0..15, h = t&63) sums 32 chunks from the
// block's contiguous 128 KiB stream (per-instr 256 B coalesced, 32-deep MLP
// x 16 waves). Then LDS-reduce + heads + argmax. Same FP order as R11.
// ---------------------------------------------------------------------------
__global__ __launch_bounds__(1024)
void k_tail(const float* __restrict__ gcn_b,
            const float* __restrict__ w1, const float* __restrict__ b1,
            const float* __restrict__ w2, const float* __restrict__ b2,
            const float* __restrict__ actions, float* __restrict__ out) {
    const int b = blockIdx.x;
    const int t = threadIdx.x;
    __shared__ float red[16][HID];
    __shared__ float pooled[HID];
    __shared__ float zbuf[N_AGENTS][HID];
    __shared__ float qbuf[N_AGENTS][N_ACT];

    // phase 1: red[kg][h] = sum of this kg's 32 chunks (contiguous 8KB each)
    {
        const int h  = t & 63;
        const int kg = t >> 6;   // 0..15
        const float* p = g_part + ((size_t)b * NCHUNK + kg * 32) * HID + h;
        float acc = 0.f;
        #pragma unroll
        for (int i = 0; i < 32; ++i)
            acc += p[(size_t)i * HID];
        red[kg][h] = acc;
    }
    __syncthreads();
    if (t < HID) {
        float acc = gcn_b[t];
        #pragma unroll
        for (int kg = 0; kg < 16; ++kg) acc += red[kg][t];
        pooled[t] = acc;
    }
    __syncthreads();

    // phase 2: z[a][k] = leaky(b1 + sum_h pooled[h] * w1[a][h][k])
    if (t < N_AGENTS * HID) {
        const int a = t >> 6, k = t & 63;
        const float* w1p = w1 + a * (HID * HID) + k;
        float acc = b1[a * HID + k];
        #pragma unroll
        for (int hh = 0; hh < HID; ++hh) acc += pooled[hh] * w1p[hh * HID];
        zbuf[a][k] = (acc >= 0.f) ? acc : NEG_SLOPE * acc;
    }
    __syncthreads();

    // phase 3: q[a][c] = b2 + sum_h z[a][h] * w2[a][h][c]
    if (t < N_AGENTS * N_ACT) {
        const int a = t / N_ACT, c = t % N_ACT;
        const float* w2p = w2 + a * (HID * N_ACT) + c;
        float acc = b2[a * N_ACT + c];
        #pragma unroll
        for (int hh = 0; hh < HID; ++hh) acc += zbuf[a][hh] * w2p[hh * N_ACT];
        qbuf[a][c] = acc;
    }
    __syncthreads();

    // phase 4: argmax over actions (first-max, matching jnp.argmax), gather
    if (t < N_AGENTS) {
        const float* ap = actions + ((size_t)t * BATCH + b) * N_ACT;
        int best = 0; float bv = ap[0];
        for (int c = 1; c < N_ACT; ++c) {
            float v = ap[c];
            if (v > bv) { bv = v; best = c; }
        }
        out[t * BATCH + b] = qbuf[t][best];
    }
}

extern "C" void kernel_launch(void* const* d_in, const int* in_sizes, int n_in,
                              void* d_out, int out_size, void* d_ws, size_t ws_size,
                              hipStream_t stream) {
    const float* u   = (const float*)d_in[0];
    // d_in[1] = binary_tensor: dead in the reference computation
    const float* act = (const float*)d_in[2];
    const float* gw  = (const float*)d_in[3];
    const float* gb  = (const float*)d_in[4];
    const float* w1  = (const float*)d_in[5];
    const float* b1  = (const float*)d_in[6];
    const float* w2  = (const float*)d_in[7];
    const float* b2  = (const float*)d_in[8];
    float* out = (float*)d_out;

    hipLaunchKernelGGL(k_fused, dim3(NCHUNK), dim3(512), 0, stream, u, gw);
    hipLaunchKernelGGL(k_tail,  dim3(BATCH),  dim3(1024), 0, stream,
                       gb, w1, b1, w2, b2, act, out);
}